// Round 3
// baseline (30.808 us; speedup 1.0000x reference)
//
#include <hip/hip_runtime.h>
#include <hip/hip_bf16.h>
#include <math.h>

// Problem constants (from reference setup_inputs)
#define BATCH   512          // bs * n_vars = 64 * 8
#define KP      3            // k_positive
#define KN      16           // k_negative
#define KTOT    (KP + KN)    // 19
#define PD      8192         // P * D = 64 * 128
#define INV_T   50.0f        // 1 / temperature (0.02)

#define SPLIT   4            // blocks per sample
#define CHUNK   (PD / SPLIT) // 2048 floats per block
#define THREADS 256          // 256 threads * 8 floats = 2048

// native clang vector type — accepted by __builtin_nontemporal_{load,store}
typedef float f32x4 __attribute__((ext_vector_type(4)));

__global__ __launch_bounds__(THREADS)
void agg_rebuild_kernel(const float* __restrict__ sim,
                        const float* __restrict__ p_enc,
                        const int*   __restrict__ neg_idx,
                        float*       __restrict__ out) {
    const int b    = blockIdx.x >> 2;        // sample index (block-uniform)
    const int part = blockIdx.x & (SPLIT-1); // chunk of the 8192 elems
    const int tid  = threadIdx.x;

    // --- softmax over 19 temperature-scaled scores.
    // b is uniform per block -> these loads scalarize (s_load); every lane
    // computes the same softmax redundantly. No LDS, no barriers.
    float w[KTOT];
    float m = -INFINITY;
    #pragma unroll
    for (int k = 0; k < KTOT; ++k) {
        w[k] = sim[b * KTOT + k] * INV_T;
        m = fmaxf(m, w[k]);
    }
    float s = 0.0f;
    #pragma unroll
    for (int k = 0; k < KTOT; ++k) {
        w[k] = __expf(w[k] - m);
        s += w[k];
    }
    const float inv = 1.0f / s;

    // --- row base pointers (block-uniform): 3 positives, 16 gathered negatives
    const float* rowp[KTOT];
    #pragma unroll
    for (int k = 0; k < KP; ++k)
        rowp[k] = p_enc + (size_t)(BATCH + b * KP + k) * PD;
    #pragma unroll
    for (int k = 0; k < KN; ++k)
        rowp[KP + k] = p_enc + (size_t)neg_idx[b * KN + k] * PD;

    // --- weighted sum: 8 consecutive floats (2x f32x4) per thread
    const int d = part * CHUNK + tid * 8;
    f32x4 acc0 = {0.f, 0.f, 0.f, 0.f};
    f32x4 acc1 = {0.f, 0.f, 0.f, 0.f};

    // positives: streamed once -> nontemporal loads (keep L2 for negatives)
    #pragma unroll
    for (int k = 0; k < KP; ++k) {
        const float wk = w[k] * inv;
        const f32x4* p = reinterpret_cast<const f32x4*>(rowp[k] + d);
        const f32x4 x0 = __builtin_nontemporal_load(p);
        const f32x4 x1 = __builtin_nontemporal_load(p + 1);
        acc0 += wk * x0;
        acc1 += wk * x1;
    }
    // negatives: reused ~16x across samples -> normal (cached) loads
    #pragma unroll
    for (int k = KP; k < KTOT; ++k) {
        const float wk = w[k] * inv;
        const f32x4* p = reinterpret_cast<const f32x4*>(rowp[k] + d);
        const f32x4 x0 = p[0];
        const f32x4 x1 = p[1];
        acc0 += wk * x0;
        acc1 += wk * x1;
    }

    f32x4* o = reinterpret_cast<f32x4*>(out + (size_t)b * PD + d);
    __builtin_nontemporal_store(acc0, o);
    __builtin_nontemporal_store(acc1, o + 1);
}

extern "C" void kernel_launch(void* const* d_in, const int* in_sizes, int n_in,
                              void* d_out, int out_size, void* d_ws, size_t ws_size,
                              hipStream_t stream) {
    const float* sim     = (const float*)d_in[0];   // [B, 19]
    const float* p_enc   = (const float*)d_in[1];   // [B*(1+KP), P, D]
    const int*   neg_idx = (const int*)d_in[2];     // [B, KN]
    float*       out     = (float*)d_out;           // [B, P, D]

    dim3 grid(BATCH * SPLIT);
    dim3 block(THREADS);
    agg_rebuild_kernel<<<grid, block, 0, stream>>>(sim, p_enc, neg_idx, out);
}

// Round 4
// 25.082 us; speedup vs baseline: 1.2283x; 1.2283x over previous
//
#include <hip/hip_runtime.h>
#include <hip/hip_bf16.h>
#include <math.h>

// Problem constants (from reference setup_inputs)
#define BATCH   512          // bs * n_vars = 64 * 8
#define KP      3            // k_positive
#define KN      16           // k_negative
#define KTOT    (KP + KN)    // 19
#define PD      8192         // P * D = 64 * 128
#define INV_T   50.0f        // 1 / temperature (0.02)

#define SPLIT   8            // blocks per sample == #XCDs: part == blockIdx%8 == XCD
#define CHUNK   (PD / SPLIT) // 1024 floats per block (4 KB slice per row)
#define THREADS 256          // 256 threads * 4 floats = 1024 (dense: 1 f32x4/thread)

// native clang vector type — accepted by __builtin_nontemporal_{load,store}
typedef float f32x4 __attribute__((ext_vector_type(4)));

__global__ __launch_bounds__(THREADS)
void agg_rebuild_kernel(const float* __restrict__ sim,
                        const float* __restrict__ p_enc,
                        const int*   __restrict__ neg_idx,
                        float*       __restrict__ out) {
    const int b    = blockIdx.x / SPLIT;   // sample index
    const int part = blockIdx.x % SPLIT;   // d-slice == XCD id (round-robin dispatch)
    const int tid  = threadIdx.x;

    __shared__ float        s_w[KTOT];
    __shared__ const float* s_row[KTOT];

    // --- softmax over 19 temperature-scaled scores (thread 0, serial: trivial)
    if (tid == 0) {
        float v[KTOT];
        float m = -INFINITY;
        #pragma unroll
        for (int k = 0; k < KTOT; ++k) {
            v[k] = sim[(size_t)b * KTOT + k] * INV_T;
            m = fmaxf(m, v[k]);
        }
        float s = 0.0f;
        #pragma unroll
        for (int k = 0; k < KTOT; ++k) {
            v[k] = __expf(v[k] - m);
            s += v[k];
        }
        const float inv = 1.0f / s;
        #pragma unroll
        for (int k = 0; k < KTOT; ++k) s_w[k] = v[k] * inv;
    }

    // --- row base pointers: 3 positives (contiguous), 16 gathered negatives
    if (tid < KTOT) {
        int row;
        if (tid < KP) row = BATCH + b * KP + tid;
        else          row = neg_idx[(size_t)b * KN + (tid - KP)];
        s_row[tid] = p_enc + (size_t)row * PD;
    }
    __syncthreads();

    // --- weighted sum of 19 rows, one f32x4 per thread, fully dense/coalesced
    const int d = part * CHUNK + tid * 4;
    f32x4 acc = {0.f, 0.f, 0.f, 0.f};

    // positives: streamed once -> nontemporal (evict-first), keep L2 for negatives.
    // Dense layout: each wave load instruction covers a contiguous 1 KB, so nt
    // cannot cause cross-instruction line refetch.
    #pragma unroll
    for (int k = 0; k < KP; ++k) {
        const float wk = s_w[k];
        const f32x4 x = __builtin_nontemporal_load(
            reinterpret_cast<const f32x4*>(s_row[k] + d));
        acc += wk * x;
    }
    // negatives: slice working set = 512 rows x 4 KB = 2 MB per XCD -> L2-resident
    #pragma unroll
    for (int k = KP; k < KTOT; ++k) {
        const float wk = s_w[k];
        const f32x4 x = *reinterpret_cast<const f32x4*>(s_row[k] + d);
        acc += wk * x;
    }

    __builtin_nontemporal_store(acc,
        reinterpret_cast<f32x4*>(out + (size_t)b * PD + d));
}

extern "C" void kernel_launch(void* const* d_in, const int* in_sizes, int n_in,
                              void* d_out, int out_size, void* d_ws, size_t ws_size,
                              hipStream_t stream) {
    const float* sim     = (const float*)d_in[0];   // [B, 19]
    const float* p_enc   = (const float*)d_in[1];   // [B*(1+KP), P, D]
    const int*   neg_idx = (const int*)d_in[2];     // [B, KN]
    float*       out     = (float*)d_out;           // [B, P, D]

    dim3 grid(BATCH * SPLIT);
    dim3 block(THREADS);
    agg_rebuild_kernel<<<grid, block, 0, stream>>>(sim, p_enc, neg_idx, out);
}

// Round 5
// 20.623 us; speedup vs baseline: 1.4939x; 1.2162x over previous
//
#include <hip/hip_runtime.h>
#include <hip/hip_bf16.h>
#include <math.h>

// Problem constants (from reference setup_inputs)
#define BATCH   512          // bs * n_vars = 64 * 8
#define KP      3            // k_positive
#define KN      16           // k_negative
#define KTOT    (KP + KN)    // 19
#define PD      8192         // P * D = 64 * 128
#define INV_T   50.0f        // 1 / temperature (0.02)

#define SPLIT   8            // blocks per sample == #XCDs (part == XCD id)
#define CHUNK   (PD / SPLIT) // 1024 floats per block (4 KB slice per row)
#define THREADS 256          // 256 threads * 4 floats = 1024 (dense 1 f32x4/thread)

typedef float f32x4 __attribute__((ext_vector_type(4)));

__global__ __launch_bounds__(THREADS)
void agg_rebuild_kernel(const float* __restrict__ sim,
                        const float* __restrict__ p_enc,
                        const int*   __restrict__ neg_idx,
                        float*       __restrict__ out) {
    const int b    = blockIdx.x >> 3;        // sample index (block-uniform)
    const int part = blockIdx.x & (SPLIT-1); // d-slice == XCD id (round-robin)
    const int tid  = threadIdx.x;

    // --- softmax over 19 temperature-scaled scores, computed redundantly by
    // every lane from block-uniform addresses: compiler scalarizes these to
    // s_load and keeps everything in SGPRs. No LDS, no barriers.
    float w[KTOT];
    float m = -INFINITY;
    #pragma unroll
    for (int k = 0; k < KTOT; ++k) {
        w[k] = sim[b * KTOT + k] * INV_T;
        m = fmaxf(m, w[k]);
    }
    float s = 0.0f;
    #pragma unroll
    for (int k = 0; k < KTOT; ++k) {
        w[k] = __expf(w[k] - m);
        s += w[k];
    }
    const float inv = 1.0f / s;

    // --- row base pointers, all block-uniform -> SGPR pairs.
    const float* rowp[KTOT];
    #pragma unroll
    for (int k = 0; k < KP; ++k)
        rowp[k] = p_enc + (size_t)(BATCH + b * KP + k) * PD;
    #pragma unroll
    for (int k = 0; k < KN; ++k)
        rowp[KP + k] = p_enc + (size_t)neg_idx[b * KN + k] * PD;

    // --- weighted sum of 19 rows, one dense f32x4 per thread (fully coalesced:
    // each wave load instruction covers one contiguous 1 KB segment).
    const int d = part * CHUNK + tid * 4;
    f32x4 acc = {0.f, 0.f, 0.f, 0.f};
    #pragma unroll
    for (int k = 0; k < KTOT; ++k) {
        const f32x4 x = *reinterpret_cast<const f32x4*>(rowp[k] + d);
        acc += (w[k] * inv) * x;
    }

    *reinterpret_cast<f32x4*>(out + (size_t)b * PD + d) = acc;
}

extern "C" void kernel_launch(void* const* d_in, const int* in_sizes, int n_in,
                              void* d_out, int out_size, void* d_ws, size_t ws_size,
                              hipStream_t stream) {
    const float* sim     = (const float*)d_in[0];   // [B, 19]
    const float* p_enc   = (const float*)d_in[1];   // [B*(1+KP), P, D]
    const int*   neg_idx = (const int*)d_in[2];     // [B, KN]
    float*       out     = (float*)d_out;           // [B, P, D]

    dim3 grid(BATCH * SPLIT);
    dim3 block(THREADS);
    agg_rebuild_kernel<<<grid, block, 0, stream>>>(sim, p_enc, neg_idx, out);
}